// Round 1
// baseline (554.998 us; speedup 1.0000x reference)
//
#include <hip/hip_runtime.h>

// TemporalAttention N=8192 D=1024, fp32 in/out, fp16-MFMA internals.
// v8: all GEMMs moved from the m97-style 128x128/BK=64 drain-at-barrier
// structure (measured 745 TF, MfmaUtil 34%) to a counted-vmcnt 4-slot
// LDS ring (T3+T4+T5 from the 8-phase family): BK=32 sub-tiles, 512 thr
// / 8 waves, per-wave 128x64 (or 64x64) output, issue sub-tile t+3 ->
// vmcnt(12) -> barrier -> 12x ds_read_b128 + 32 MFMA (setprio) -> barrier.
// vmcnt never drains to 0 in the main loop; 3 sub-tiles stay in flight.
// LDS chunk swizzle: 32-col rows (64 B), stored chunk = c ^ ((row>>1)&3),
// applied via pre-swizzled global source (gload_lds dest stays linear).
// Tile shapes keep every grid at >=256 workgroups (1 block/CU).

using half8   = __attribute__((ext_vector_type(8))) _Float16;
using half4   = __attribute__((ext_vector_type(4))) _Float16;
using floatx4 = __attribute__((ext_vector_type(4))) float;

__device__ __forceinline__ void gload_lds16(const void* g, void* l) {
  __builtin_amdgcn_global_load_lds((const __attribute__((address_space(1))) void*)g,
                                   (__attribute__((address_space(3))) void*)l,
                                   16, 0, 0);
}

template<int N> __device__ __forceinline__ void waitv() {
  if constexpr (N == 12)      asm volatile("s_waitcnt vmcnt(12)" ::: "memory");
  else if constexpr (N == 9)  asm volatile("s_waitcnt vmcnt(9)"  ::: "memory");
  else if constexpr (N == 8)  asm volatile("s_waitcnt vmcnt(8)"  ::: "memory");
  else if constexpr (N == 6)  asm volatile("s_waitcnt vmcnt(6)"  ::: "memory");
  else if constexpr (N == 4)  asm volatile("s_waitcnt vmcnt(4)"  ::: "memory");
  else if constexpr (N == 3)  asm volatile("s_waitcnt vmcnt(3)"  ::: "memory");
  else                        asm volatile("s_waitcnt vmcnt(0)"  ::: "memory");
}

// Ring-buffered K-loop: C[BMxBN] += A(rows,lda) * B(rows,ldb)^T, fp16 in,
// fp32 accum. 8 waves in a WM x WN grid; per-wave (BM/WM)x(BN/WN) output.
// As/Bs: 4 slots of [BM][32] / [BN][32] halfs (linear; swizzle via source).
template<int BM, int BN, int WM, int WN, int MI, int NJ>
__device__ __forceinline__ void kloop_ring(
    const _Float16* __restrict__ A, const _Float16* __restrict__ B,
    long rowBase, long colBase, int lda, int ldb, int K,
    _Float16* __restrict__ As, _Float16* __restrict__ Bs,
    floatx4 (&acc)[MI][NJ])
{
  constexpr int LA = BM / 128, LB = BN / 128;   // gload_lds per wave/op
  constexpr int ISS = LA + LB;                  // vmcnt ops per sub-tile
  const int tid = threadIdx.x;
  const int w = tid >> 6, lane = tid & 63;
  const int q = lane >> 4, l15 = lane & 15;
  const int wr = w / WN, wcn = w & (WN - 1);

  // Staging: LDS linear (gload_lds dest = uniform base + lane*16); global
  // source chunk pre-swizzled: sc = c ^ ((row>>1)&3), c = lane&3.
  const int sc = (((lane & 3) ^ ((lane >> 3) & 3)) << 3);
  const _Float16* Agp[LA]; int Aoff[LA];
  const _Float16* Bgp[LB]; int Boff[LB];
#pragma unroll
  for (int p = 0; p < LA; ++p) {
    const int row = ((w * (BM * 4) + p * 512 + lane * 8) >> 5);
    Agp[p] = A + (rowBase + row) * (long)lda + sc;
    Aoff[p] = w * (BM * 4) + p * 512;
  }
#pragma unroll
  for (int p = 0; p < LB; ++p) {
    const int row = ((w * (BN * 4) + p * 512 + lane * 8) >> 5);
    Bgp[p] = B + (colBase + row) * (long)ldb + sc;
    Boff[p] = w * (BN * 4) + p * 512;
  }

  // Fragment reads: row R chunk q lives at position q ^ ((R>>1)&3);
  // (R>>1)&3 == (l15>>1)&3 for all frag rows (16-row strides are %4==0).
  const int pRd   = (q ^ ((l15 >> 1) & 3)) << 3;
  const int aBase = (wr * (BM / WM) + l15) * 32 + pRd;
  const int bBase = (wcn * (BN / WN) + l15) * 32 + pRd;

  auto issue = [&](int t) {
    const int s = t & 3;
    const long ko = (long)t * 32;
    _Float16* Asl = As + s * (BM * 32);
    _Float16* Bsl = Bs + s * (BN * 32);
#pragma unroll
    for (int p = 0; p < LA; ++p) gload_lds16(Agp[p] + ko, Asl + Aoff[p]);
#pragma unroll
    for (int p = 0; p < LB; ++p) gload_lds16(Bgp[p] + ko, Bsl + Boff[p]);
  };

  auto compute = [&](int slot) {
    const _Float16* Asl = As + slot * (BM * 32);
    const _Float16* Bsl = Bs + slot * (BN * 32);
    half8 bfr[NJ], afr[MI];
#pragma unroll
    for (int j = 0; j < NJ; ++j) bfr[j] = *(const half8*)&Bsl[bBase + j * 512];
#pragma unroll
    for (int i = 0; i < MI; ++i) afr[i] = *(const half8*)&Asl[aBase + i * 512];
    __builtin_amdgcn_s_setprio(1);
#pragma unroll
    for (int i = 0; i < MI; ++i)
#pragma unroll
      for (int j = 0; j < NJ; ++j)
        acc[i][j] = __builtin_amdgcn_mfma_f32_16x16x32_f16(afr[i], bfr[j], acc[i][j], 0, 0, 0);
    __builtin_amdgcn_s_setprio(0);
  };

  const int NT = K >> 5;          // BK=32 sub-tiles
  issue(0); issue(1); issue(2);   // 3-deep prefetch
  for (int t = 0; t < NT - 3; ++t) {
    issue(t + 3);                 // overwrites slot (t-1)&3: reads of
                                  // sub-tile t-1 completed before its
                                  // closing barrier -> safe.
    waitv<3 * ISS>();             // own loads of sub-tile t landed;
                                  // t+1..t+3 stay in flight (never 0).
    __builtin_amdgcn_s_barrier(); // all waves' writes of sub-tile t visible
    compute(t & 3);
    __builtin_amdgcn_s_barrier(); // all reads of slot t&3 done
  }
  waitv<2 * ISS>(); __builtin_amdgcn_s_barrier();
  compute((NT - 3) & 3);          __builtin_amdgcn_s_barrier();
  waitv<1 * ISS>(); __builtin_amdgcn_s_barrier();
  compute((NT - 2) & 3);          __builtin_amdgcn_s_barrier();
  waitv<0>();       __builtin_amdgcn_s_barrier();
  compute((NT - 1) & 3);
}

// BIAS_MODE: 0 none, 1 add per-col, 2 add per-row, 3 MUL per-row (invL).
// OUT_MODE: 0 fp16, 2 fp32.  SWZ: XCD grouping via ty = bflat % gridDim.y.
template<int BM, int BN, int WM, int WN, int BIAS_MODE, int OUT_MODE, int SWZ>
__global__ __launch_bounds__(512, 2)
void gemm256_k(const _Float16* __restrict__ A, const _Float16* __restrict__ B,
               void* __restrict__ Cout, const float* __restrict__ bias,
               int lda, int ldb, int ldc, int K, float outScale)
{
  constexpr int MI = BM / WM / 16, NJ = BN / WN / 16;
  __shared__ __align__(16) _Float16 As[4 * BM * 32];
  __shared__ __align__(16) _Float16 Bs[4 * BN * 32];

  int tx, ty;
  if (SWZ) {
    const int bflat = blockIdx.y * gridDim.x + blockIdx.x;  // dispatch-linear
    ty = bflat % gridDim.y;
    tx = bflat / gridDim.y;
  } else {
    tx = blockIdx.x; ty = blockIdx.y;
  }
  const long rowBase = (long)ty * BM;
  const long colBase = (long)tx * BN;

  floatx4 acc[MI][NJ] = {};
  kloop_ring<BM, BN, WM, WN, MI, NJ>(A, B, rowBase, colBase, lda, ldb, K, As, Bs, acc);

  const int tid = threadIdx.x;
  const int w = tid >> 6, lane = tid & 63;
  const int q = lane >> 4, l15 = lane & 15;
  const int wr = w / WN, wcn = w & (WN - 1);
#pragma unroll
  for (int i = 0; i < MI; ++i) {
#pragma unroll
    for (int r = 0; r < 4; ++r) {
      const long rowg = rowBase + wr * (BM / WM) + 16 * i + q * 4 + r;
#pragma unroll
      for (int j = 0; j < NJ; ++j) {
        const long colg = colBase + wcn * (BN / WN) + 16 * j + l15;
        float v = acc[i][j][r];
        if (BIAS_MODE == 1) v += bias[colg];
        if (BIAS_MODE == 2) v += bias[rowg];
        if (BIAS_MODE == 3) v *= bias[rowg];
        v *= outScale;
        if (OUT_MODE == 2) ((float*)Cout)[rowg * ldc + colg] = v;
        else               ((_Float16*)Cout)[rowg * ldc + colg] = (_Float16)v;
      }
    }
  }
}

// U = exp(qkScale*(Q*K^T) + decay_bias - 4), fp16; per-(row,col-tile) sums.
// Same ring engine, 256x256 tile, fused exp epilogue.
__global__ __launch_bounds__(512, 2)
void gemm_stats256_k(const _Float16* __restrict__ A, const _Float16* __restrict__ B,
                     const float* __restrict__ ts, _Float16* __restrict__ U,
                     float* __restrict__ part, int lda, int ldb, int N, int K,
                     float qkScale)
{
  constexpr int BM = 256, BN = 256, WM = 2, WN = 4, MI = 8, NJ = 4;
  __shared__ __align__(16) _Float16 As[4 * BM * 32];
  __shared__ __align__(16) _Float16 Bs[4 * BN * 32];
  __shared__ float trs[256], tcs[256];
  __shared__ float sL[2][4][128];
  const int tid = threadIdx.x;
  const long rowBase = (long)blockIdx.y * 256;
  const long colBase = (long)blockIdx.x * 256;

  if (tid < 256) {
    trs[tid] = ts[rowBase + tid];
    tcs[tid] = ts[colBase + tid];
  }

  floatx4 acc[MI][NJ] = {};
  kloop_ring<BM, BN, WM, WN, MI, NJ>(A, B, rowBase, colBase, lda, ldb, K, As, Bs, acc);

  const int w = tid >> 6, lane = tid & 63;
  const int q = lane >> 4, l15 = lane & 15;
  const int wr = w >> 2, wcn = w & 3;
  const float inv_td = 1.0f / 86400.0f;
  // u = exp(s - 4); s = qk/32 + log-decay ~ qk/32 - |dt|/TD (exact to 2.2e-6).
#pragma unroll
  for (int i = 0; i < 8; ++i) {
#pragma unroll
    for (int r = 0; r < 4; ++r) {
      const int rowl = wr * 128 + 16 * i + q * 4 + r;
      const float tr = trs[rowl];
      float ls = 0.0f;
#pragma unroll
      for (int j = 0; j < 4; ++j) {
        const int coll = wcn * 64 + 16 * j + l15;
        const float sv = acc[i][j][r] * qkScale
                       - fabsf(tr - tcs[coll]) * inv_td - 4.0f;
        const float u = __expf(sv);
        ls += u;
        U[(rowBase + rowl) * (long)N + (colBase + coll)] = (_Float16)u;
      }
      for (int mask = 1; mask <= 8; mask <<= 1)
        ls += __shfl_xor(ls, mask, 64);
      if (l15 == 0) sL[wr][wcn][16 * i + 4 * q + r] = ls;
    }
  }
  __syncthreads();
  if (tid < 256) {
    const int wr2 = tid >> 7, rl = tid & 127;
    part[(rowBase + tid) * 32 + blockIdx.x] =
        sL[wr2][0][rl] + sL[wr2][1][rl] + sL[wr2][2][rl] + sL[wr2][3][rl];
  }
}

__global__ void combine_k(const float* __restrict__ part, float* __restrict__ invL) {
  const int r = blockIdx.x * 256 + threadIdx.x;
  float L = 0.0f;
  for (int c = 0; c < 32; ++c) L += part[(long)r * 32 + c];
  invL[r] = 1.0f / L;
}

// fp32 -> fp16, 4/thread
__global__ void cvt_k(const float* __restrict__ in, _Float16* __restrict__ out, int n) {
  const int i = (blockIdx.x * 256 + threadIdx.x) * 4;
  if (i >= n) return;
  const float4 v = *(const float4*)(in + i);
  half4 o = { (_Float16)v.x, (_Float16)v.y, (_Float16)v.z, (_Float16)v.w };
  *(half4*)(out + i) = o;
}

extern "C" void kernel_launch(void* const* d_in, const int* in_sizes, int n_in,
                              void* d_out, int out_size, void* d_ws, size_t ws_size,
                              hipStream_t stream)
{
  (void)in_sizes; (void)n_in; (void)out_size; (void)ws_size;
  const int N = 8192, D = 1024;
  const float* x  = (const float*)d_in[0];
  const float* ts = (const float*)d_in[1];
  const float* Wq = (const float*)d_in[2];
  const float* bq = (const float*)d_in[3];
  const float* Wk = (const float*)d_in[4];
  const float* bk = (const float*)d_in[5];
  const float* Wv = (const float*)d_in[6];
  const float* bv = (const float*)d_in[7];

  char* p = (char*)d_ws;
  auto grab = [&](size_t bytes) {
    char* r = p;
    p += (bytes + 255) & ~(size_t)255;
    return r;
  };
  _Float16* xh    = (_Float16*)grab((size_t)N * D * 2);
  _Float16* wqkh  = (_Float16*)grab((size_t)2 * D * D * 2); // Wq rows then Wk rows
  _Float16* wvh   = (_Float16*)grab((size_t)D * D * 2);
  _Float16* QKcat = (_Float16*)grab((size_t)N * 2 * D * 2); // [N x 2D], Q | K
  _Float16* VTh   = (_Float16*)grab((size_t)D * N * 2);     // V^T [D x N]
  _Float16* Uh    = (_Float16*)grab((size_t)N * N * 2);     // U = exp(S - 4)
  float*    part  = (float*)grab((size_t)N * 32 * sizeof(float));
  float*    invL  = (float*)grab((size_t)N * sizeof(float));
  float*    bcat  = (float*)grab((size_t)2 * D * sizeof(float));

  cvt_k<<<N * D / 1024, 256, 0, stream>>>(x,  xh,  N * D);
  cvt_k<<<D * D / 1024, 256, 0, stream>>>(Wq, wqkh,         D * D);
  cvt_k<<<D * D / 1024, 256, 0, stream>>>(Wk, wqkh + D * D, D * D);
  cvt_k<<<D * D / 1024, 256, 0, stream>>>(Wv, wvh, D * D);
  hipMemcpyAsync(bcat,     bq, D * sizeof(float), hipMemcpyDeviceToDevice, stream);
  hipMemcpyAsync(bcat + D, bk, D * sizeof(float), hipMemcpyDeviceToDevice, stream);

  dim3 blk(512);
  // [Q | K] = x [Wq;Wk]^T + [bq|bk]   (unscaled; 1/32 folded into stats)
  // 256x256 tiles -> grid (8,32) = 256 wg.
  gemm256_k<256, 256, 2, 4, 1, 0, 0><<<dim3(2 * D / 256, N / 256), blk, 0, stream>>>(
      xh, wqkh, QKcat, bcat, D, D, 2 * D, D, 1.0f);
  // V^T = Wv x^T + bv (bias per output row = channel d); 128x256 -> 256 wg.
  gemm256_k<128, 256, 2, 4, 2, 0, 0><<<dim3(N / 256, D / 128), blk, 0, stream>>>(
      wvh, xh, VTh, bv, D, D, N, D, 1.0f);
  // U = exp(QK^T/32 + decay - 4) + partial row sums; 256x256 -> 1024 wg.
  gemm_stats256_k<<<dim3(N / 256, N / 256), blk, 0, stream>>>(
      QKcat, QKcat + D, ts, Uh, part, 2 * D, 2 * D, N, D, 1.0f / 32.0f);
  combine_k<<<N / 256, 256, 0, stream>>>(part, invL);
  // O = (U V) * invL — 256x128 tiles -> grid (8,32) = 256 wg, XCD-swizzled.
  gemm256_k<256, 128, 4, 2, 3, 2, 1><<<dim3(D / 128, N / 256), blk, 0, stream>>>(
      Uh, VTh, d_out, invL, N, N, D, N, 1.0f);
}

// Round 2
// 494.018 us; speedup vs baseline: 1.1234x; 1.1234x over previous
//
#include <hip/hip_runtime.h>

// TemporalAttention N=8192 D=1024, fp32 in/out, fp16-MFMA internals.
// v9: counted-vmcnt kept, BK back to 64 (32-64 MFMA per barrier-pair),
// ring depth sized to the latency regime:
//  - Engine A: 256x256, BK=64, 2-slot dbuf (128KB), vmcnt(8), 8 waves
//    2Mx4N (per-wave 128x64). For L2-warm kernels (QK-proj, stats).
//  - Engine B: 256x128, BK=64, 3-slot ring (144KB), vmcnt(12): 2 K-tiles
//    (~1100cy of work) in flight >= ~900cy HBM latency. For PV (streams
//    128MB U from HBM) and V-proj.
// LDS layout: [row][64] halfs, chunk c stored at c^(row&7) (v7-proven,
// 0 bank conflicts), applied via pre-swizzled global source so
// global_load_lds dest stays linear. vmcnt never drains to 0 mid-loop.

using half8   = __attribute__((ext_vector_type(8))) _Float16;
using half4   = __attribute__((ext_vector_type(4))) _Float16;
using floatx4 = __attribute__((ext_vector_type(4))) float;

__device__ __forceinline__ void gload_lds16(const void* g, void* l) {
  __builtin_amdgcn_global_load_lds((const __attribute__((address_space(1))) void*)g,
                                   (__attribute__((address_space(3))) void*)l,
                                   16, 0, 0);
}

template<int N> __device__ __forceinline__ void waitv() {
  if constexpr (N == 12)     asm volatile("s_waitcnt vmcnt(12)" ::: "memory");
  else if constexpr (N == 8) asm volatile("s_waitcnt vmcnt(8)"  ::: "memory");
  else if constexpr (N == 6) asm volatile("s_waitcnt vmcnt(6)"  ::: "memory");
  else                       asm volatile("s_waitcnt vmcnt(0)"  ::: "memory");
}

// Ring-buffered BK=64 K-loop: C[BMxBN] += A(rows,lda)*B(rows,ldb)^T.
// 8 waves as WM x WN; per-wave (BM/WM)x(BN/WN). SLOTS in {2,3}.
// LDS slot: [rows][64] halfs, chunk (16B) c at position c^(row&7).
template<int BM, int BN, int WM, int WN, int SLOTS, int MI, int NJ>
__device__ __forceinline__ void kloop64(
    const _Float16* __restrict__ A, const _Float16* __restrict__ B,
    long rowBase, long colBase, int lda, int ldb, int K,
    _Float16* __restrict__ As, _Float16* __restrict__ Bs,
    floatx4 (&acc)[MI][NJ])
{
  static_assert(MI == BM / WM / 16 && NJ == BN / WN / 16);
  constexpr int LA = BM / 64, LB = BN / 64;   // gload_lds per thread/K-tile
  constexpr int ISS = LA + LB;
  const int tid = threadIdx.x;
  const int w = tid >> 6, lane = tid & 63;
  const int q = lane >> 4, l15 = lane & 15;
  const int wr = w / WN, wcn = w & (WN - 1);

  // Staging pass p covers rows [p*64, p*64+64); lane source chunk is
  // pre-swizzled: row&7 == lane>>3, chunk == lane&7.
  const int sc = ((lane & 7) ^ (lane >> 3)) << 3;
  const _Float16* Agp[LA]; const _Float16* Bgp[LB];
#pragma unroll
  for (int p = 0; p < LA; ++p)
    Agp[p] = A + (rowBase + p * 64 + (tid >> 3)) * (long)lda + sc;
#pragma unroll
  for (int p = 0; p < LB; ++p)
    Bgp[p] = B + (colBase + p * 64 + (tid >> 3)) * (long)ldb + sc;
  const int ldsOff = tid * 8;                 // halfs; +p*4096 per pass

  const int aRow = wr * (BM / WM) + l15;      // frag rows (R&7 == l15&7)
  const int bRow = wcn * (BN / WN) + l15;
  const int cx = l15 & 7;

  auto issue = [&](int t, int slot) {
    const int ko = t << 6;
    _Float16* Asl = As + slot * (BM * 64);
    _Float16* Bsl = Bs + slot * (BN * 64);
#pragma unroll
    for (int p = 0; p < LA; ++p) gload_lds16(Agp[p] + ko, Asl + p * 4096 + ldsOff);
#pragma unroll
    for (int p = 0; p < LB; ++p) gload_lds16(Bgp[p] + ko, Bsl + p * 4096 + ldsOff);
  };

  auto compute = [&](int slot) {
    const _Float16* Asl = As + slot * (BM * 64);
    const _Float16* Bsl = Bs + slot * (BN * 64);
#pragma unroll
    for (int kk = 0; kk < 2; ++kk) {
      const int pc = ((kk * 4 + q) ^ cx) << 3;
      half8 bfr[NJ];
#pragma unroll
      for (int j = 0; j < NJ; ++j)
        bfr[j] = *(const half8*)&Bsl[(bRow + 16 * j) * 64 + pc];
      half8 afr[MI];
#pragma unroll
      for (int i = 0; i < MI; ++i)
        afr[i] = *(const half8*)&Asl[(aRow + 16 * i) * 64 + pc];
      __builtin_amdgcn_s_setprio(1);
#pragma unroll
      for (int i = 0; i < MI; ++i)
#pragma unroll
        for (int j = 0; j < NJ; ++j)
          acc[i][j] = __builtin_amdgcn_mfma_f32_16x16x32_f16(afr[i], bfr[j], acc[i][j], 0, 0, 0);
      __builtin_amdgcn_s_setprio(0);
    }
  };

  const int NT = K >> 6;
  if constexpr (SLOTS == 2) {
    issue(0, 0);
    int cs = 0;
    for (int t = 0; t < NT - 1; ++t) {
      issue(t + 1, cs ^ 1);           // slot cs^1: last read at t-1, done
      waitv<ISS>();                   // tile t landed; t+1 stays in flight
      __builtin_amdgcn_s_barrier();   // all waves' writes of t visible
      compute(cs);
      __builtin_amdgcn_s_barrier();   // all reads of slot cs done
      cs ^= 1;
    }
    waitv<0>(); __builtin_amdgcn_s_barrier();
    compute(cs);
  } else {
    static_assert(SLOTS == 3);
    issue(0, 0); issue(1, 1);
    int cs = 0, is = 2;
    for (int t = 0; t < NT - 2; ++t) {
      issue(t + 2, is);               // slot (t+2)%3: last read at t-1
      waitv<2 * ISS>();               // tile t landed; t+1,t+2 in flight
      __builtin_amdgcn_s_barrier();
      compute(cs);
      __builtin_amdgcn_s_barrier();
      cs = (cs == 2) ? 0 : cs + 1;
      is = (is == 2) ? 0 : is + 1;
    }
    waitv<ISS>(); __builtin_amdgcn_s_barrier();
    compute(cs);  __builtin_amdgcn_s_barrier();
    cs = (cs == 2) ? 0 : cs + 1;
    waitv<0>();   __builtin_amdgcn_s_barrier();
    compute(cs);
  }
}

// BIAS_MODE: 0 none, 1 add per-col, 2 add per-row, 3 MUL per-row (invL).
// OUT_MODE: 0 fp16, 2 fp32.  SWZ: XCD grouping via ty = bflat % gridDim.y.
template<int BM, int BN, int WM, int WN, int SLOTS, int BIAS_MODE, int OUT_MODE, int SWZ>
__global__ __launch_bounds__(512, 2)
void gemm256_k(const _Float16* __restrict__ A, const _Float16* __restrict__ B,
               void* __restrict__ Cout, const float* __restrict__ bias,
               int lda, int ldb, int ldc, int K, float outScale)
{
  constexpr int MI = BM / WM / 16, NJ = BN / WN / 16;
  __shared__ __align__(16) _Float16 As[SLOTS * BM * 64];
  __shared__ __align__(16) _Float16 Bs[SLOTS * BN * 64];

  int tx, ty;
  if (SWZ) {
    const int bflat = blockIdx.y * gridDim.x + blockIdx.x;  // dispatch-linear
    ty = bflat % gridDim.y;
    tx = bflat / gridDim.y;
  } else {
    tx = blockIdx.x; ty = blockIdx.y;
  }
  const long rowBase = (long)ty * BM;
  const long colBase = (long)tx * BN;

  floatx4 acc[MI][NJ] = {};
  kloop64<BM, BN, WM, WN, SLOTS, MI, NJ>(A, B, rowBase, colBase, lda, ldb, K, As, Bs, acc);

  const int tid = threadIdx.x;
  const int w = tid >> 6, lane = tid & 63;
  const int q = lane >> 4, l15 = lane & 15;
  const int wr = w / WN, wcn = w & (WN - 1);
#pragma unroll
  for (int i = 0; i < MI; ++i) {
#pragma unroll
    for (int r = 0; r < 4; ++r) {
      const long rowg = rowBase + wr * (BM / WM) + 16 * i + q * 4 + r;
#pragma unroll
      for (int j = 0; j < NJ; ++j) {
        const long colg = colBase + wcn * (BN / WN) + 16 * j + l15;
        float v = acc[i][j][r];
        if (BIAS_MODE == 1) v += bias[colg];
        if (BIAS_MODE == 2) v += bias[rowg];
        if (BIAS_MODE == 3) v *= bias[rowg];
        v *= outScale;
        if (OUT_MODE == 2) ((float*)Cout)[rowg * ldc + colg] = v;
        else               ((_Float16*)Cout)[rowg * ldc + colg] = (_Float16)v;
      }
    }
  }
}

// U = exp(qkScale*(Q*K^T) + decay_bias - 4), fp16; per-(row,col-tile) sums.
// Engine A (256x256, 2-slot) + fused exp epilogue (validated in v8).
__global__ __launch_bounds__(512, 2)
void gemm_stats256_k(const _Float16* __restrict__ A, const _Float16* __restrict__ B,
                     const float* __restrict__ ts, _Float16* __restrict__ U,
                     float* __restrict__ part, int lda, int ldb, int N, int K,
                     float qkScale)
{
  constexpr int BM = 256, BN = 256, WM = 2, WN = 4, MI = 8, NJ = 4;
  __shared__ __align__(16) _Float16 As[2 * BM * 64];
  __shared__ __align__(16) _Float16 Bs[2 * BN * 64];
  __shared__ float trs[256], tcs[256];
  __shared__ float sL[2][4][128];
  const int tid = threadIdx.x;
  const long rowBase = (long)blockIdx.y * 256;
  const long colBase = (long)blockIdx.x * 256;

  if (tid < 256) {
    trs[tid] = ts[rowBase + tid];
    tcs[tid] = ts[colBase + tid];
  }

  floatx4 acc[MI][NJ] = {};
  kloop64<BM, BN, WM, WN, 2, MI, NJ>(A, B, rowBase, colBase, lda, ldb, K, As, Bs, acc);

  const int w = tid >> 6, lane = tid & 63;
  const int q = lane >> 4, l15 = lane & 15;
  const int wr = w >> 2, wcn = w & 3;
  const float inv_td = 1.0f / 86400.0f;
  // u = exp(s - 4); s = qk/32 + log-decay ~ qk/32 - |dt|/TD (exact to 2.2e-6).
#pragma unroll
  for (int i = 0; i < 8; ++i) {
#pragma unroll
    for (int r = 0; r < 4; ++r) {
      const int rowl = wr * 128 + 16 * i + q * 4 + r;
      const float tr = trs[rowl];
      float ls = 0.0f;
#pragma unroll
      for (int j = 0; j < 4; ++j) {
        const int coll = wcn * 64 + 16 * j + l15;
        const float sv = acc[i][j][r] * qkScale
                       - fabsf(tr - tcs[coll]) * inv_td - 4.0f;
        const float u = __expf(sv);
        ls += u;
        U[(rowBase + rowl) * (long)N + (colBase + coll)] = (_Float16)u;
      }
      for (int mask = 1; mask <= 8; mask <<= 1)
        ls += __shfl_xor(ls, mask, 64);
      if (l15 == 0) sL[wr][wcn][16 * i + 4 * q + r] = ls;
    }
  }
  __syncthreads();
  if (tid < 256) {
    const int wr2 = tid >> 7, rl = tid & 127;
    part[(rowBase + tid) * 32 + blockIdx.x] =
        sL[wr2][0][rl] + sL[wr2][1][rl] + sL[wr2][2][rl] + sL[wr2][3][rl];
  }
}

__global__ void combine_k(const float* __restrict__ part, float* __restrict__ invL) {
  const int r = blockIdx.x * 256 + threadIdx.x;
  float L = 0.0f;
  for (int c = 0; c < 32; ++c) L += part[(long)r * 32 + c];
  invL[r] = 1.0f / L;
}

// fp32 -> fp16, 4/thread
__global__ void cvt_k(const float* __restrict__ in, _Float16* __restrict__ out, int n) {
  const int i = (blockIdx.x * 256 + threadIdx.x) * 4;
  if (i >= n) return;
  const float4 v = *(const float4*)(in + i);
  half4 o = { (_Float16)v.x, (_Float16)v.y, (_Float16)v.z, (_Float16)v.w };
  *(half4*)(out + i) = o;
}

extern "C" void kernel_launch(void* const* d_in, const int* in_sizes, int n_in,
                              void* d_out, int out_size, void* d_ws, size_t ws_size,
                              hipStream_t stream)
{
  (void)in_sizes; (void)n_in; (void)out_size; (void)ws_size;
  const int N = 8192, D = 1024;
  const float* x  = (const float*)d_in[0];
  const float* ts = (const float*)d_in[1];
  const float* Wq = (const float*)d_in[2];
  const float* bq = (const float*)d_in[3];
  const float* Wk = (const float*)d_in[4];
  const float* bk = (const float*)d_in[5];
  const float* Wv = (const float*)d_in[6];
  const float* bv = (const float*)d_in[7];

  char* p = (char*)d_ws;
  auto grab = [&](size_t bytes) {
    char* r = p;
    p += (bytes + 255) & ~(size_t)255;
    return r;
  };
  _Float16* xh    = (_Float16*)grab((size_t)N * D * 2);
  _Float16* wqkh  = (_Float16*)grab((size_t)2 * D * D * 2); // Wq rows then Wk rows
  _Float16* wvh   = (_Float16*)grab((size_t)D * D * 2);
  _Float16* QKcat = (_Float16*)grab((size_t)N * 2 * D * 2); // [N x 2D], Q | K
  _Float16* VTh   = (_Float16*)grab((size_t)D * N * 2);     // V^T [D x N]
  _Float16* Uh    = (_Float16*)grab((size_t)N * N * 2);     // U = exp(S - 4)
  float*    part  = (float*)grab((size_t)N * 32 * sizeof(float));
  float*    invL  = (float*)grab((size_t)N * sizeof(float));
  float*    bcat  = (float*)grab((size_t)2 * D * sizeof(float));

  cvt_k<<<N * D / 1024, 256, 0, stream>>>(x,  xh,  N * D);
  cvt_k<<<D * D / 1024, 256, 0, stream>>>(Wq, wqkh,         D * D);
  cvt_k<<<D * D / 1024, 256, 0, stream>>>(Wk, wqkh + D * D, D * D);
  cvt_k<<<D * D / 1024, 256, 0, stream>>>(Wv, wvh, D * D);
  hipMemcpyAsync(bcat,     bq, D * sizeof(float), hipMemcpyDeviceToDevice, stream);
  hipMemcpyAsync(bcat + D, bk, D * sizeof(float), hipMemcpyDeviceToDevice, stream);

  dim3 blk(512);
  // [Q | K] = x [Wq;Wk]^T + [bq|bk]; engine A 256x256 -> grid (8,32)=256 wg.
  gemm256_k<256, 256, 2, 4, 2, 1, 0, 0><<<dim3(2 * D / 256, N / 256), blk, 0, stream>>>(
      xh, wqkh, QKcat, bcat, D, D, 2 * D, D, 1.0f);
  // V^T = Wv x^T + bv; engine B 256x128 -> grid (64,4)=256 wg.
  gemm256_k<256, 128, 4, 2, 3, 2, 0, 0><<<dim3(N / 128, D / 256), blk, 0, stream>>>(
      wvh, xh, VTh, bv, D, D, N, D, 1.0f);
  // U = exp(QK^T/32 + decay - 4) + partial row sums; engine A, 1024 wg.
  gemm_stats256_k<<<dim3(N / 256, N / 256), blk, 0, stream>>>(
      QKcat, QKcat + D, ts, Uh, part, 2 * D, 2 * D, N, D, 1.0f / 32.0f);
  combine_k<<<N / 256, 256, 0, stream>>>(part, invL);
  // O = (U V) * invL; engine B 256x128 3-slot -> grid (8,32)=256 wg, XCD swz.
  gemm256_k<256, 128, 4, 2, 3, 3, 2, 1><<<dim3(D / 128, N / 256), blk, 0, stream>>>(
      Uh, VTh, d_out, invL, N, N, D, N, 1.0f);
}

// Round 3
// 487.019 us; speedup vs baseline: 1.1396x; 1.0144x over previous
//
#include <hip/hip_runtime.h>

// TemporalAttention N=8192 D=1024, fp32 in/out, fp16-MFMA internals.
// v10: v9's ring/slot discipline kept verbatim (proven race-free), but each
// K-tile's compute is split into m201-style sub-phases:
//   {ds_read this phase's a-frags (b-frags reg-held from ph0)
//    | issue a slice of tile t+SLOTS-1's global_load_lds}
//   -> s_barrier -> lgkmcnt(0)+sched_barrier(0) -> setprio(1)
//   -> 16-MFMA cluster -> setprio(0) -> [tile-end: counted waitv] -> barrier
// Engine A: 256x256, 2-slot, 4 phases (L2-hot kernels: QK-proj, stats);
//   tile-end waitv(0) at ~2-phase distance (covers L2 ~250cy).
// Engine B: 256x128, 3-slot, 2 phases (HBM-streamed: PV, V-proj);
//   tile-end waitv(6) -- never drains; issue-to-use ~5 phases > 900cy HBM.
// LDS layout + XOR chunk swizzle + frag addressing identical to v9
// (measured 0 bank conflicts).

using half8   = __attribute__((ext_vector_type(8))) _Float16;
using half4   = __attribute__((ext_vector_type(4))) _Float16;
using floatx4 = __attribute__((ext_vector_type(4))) float;

__device__ __forceinline__ void gload_lds16(const void* g, void* l) {
  __builtin_amdgcn_global_load_lds((const __attribute__((address_space(1))) void*)g,
                                   (__attribute__((address_space(3))) void*)l,
                                   16, 0, 0);
}

template<int N> __device__ __forceinline__ void waitv() {
  if constexpr (N == 6) asm volatile("s_waitcnt vmcnt(6)" ::: "memory");
  else                  asm volatile("s_waitcnt vmcnt(0)" ::: "memory");
}

// Phase-split ring K-loop: C[BMxBN] += A(rows,lda)*B(rows,ldb)^T.
// 8 waves as WM x WN; per-wave (BM/WM)x(BN/WN). SLOTS in {2,3}; PH phases.
template<int BM, int BN, int WM, int WN, int SLOTS, int PH, int MI, int NJ>
__device__ __forceinline__ void kloop_f(
    const _Float16* __restrict__ A, const _Float16* __restrict__ B,
    long rowBase, long colBase, int lda, int ldb, int K,
    _Float16* __restrict__ As, _Float16* __restrict__ Bs,
    floatx4 (&acc)[MI][NJ])
{
  static_assert(MI == BM / WM / 16 && NJ == BN / WN / 16 && MI % PH == 0);
  constexpr int LA = BM / 64, LB = BN / 64;   // gloads per thread per op
  constexpr int RP = MI / PH;                 // frag-rows per phase
  const int tid = threadIdx.x;
  const int w = tid >> 6, lane = tid & 63;
  const int q = lane >> 4, l15 = lane & 15;
  const int wr = w / WN, wcn = w & (WN - 1);

  // Staging (v9-proven): pass p covers rows [p*64, p*64+64); source chunk
  // pre-swizzled so LDS dest stays linear: chunk c stored at c^(row&7).
  const int sc = ((lane & 7) ^ (lane >> 3)) << 3;
  const _Float16* Agp[LA]; const _Float16* Bgp[LB];
#pragma unroll
  for (int p = 0; p < LA; ++p)
    Agp[p] = A + (rowBase + p * 64 + (tid >> 3)) * (long)lda + sc;
#pragma unroll
  for (int p = 0; p < LB; ++p)
    Bgp[p] = B + (colBase + p * 64 + (tid >> 3)) * (long)ldb + sc;
  const int ldsOff = tid * 8;

  const int aRow = wr * (BM / WM) + l15;
  const int bRow = wcn * (BN / WN) + l15;
  const int cx = l15 & 7;

  auto issueA = [&](int t, int s) {
    _Float16* Asl = As + s * (BM * 64);
    const int ko = t << 6;
#pragma unroll
    for (int p = 0; p < LA; ++p) gload_lds16(Agp[p] + ko, Asl + p * 4096 + ldsOff);
  };
  auto issueB = [&](int t, int s) {
    _Float16* Bsl = Bs + s * (BN * 64);
    const int ko = t << 6;
#pragma unroll
    for (int p = 0; p < LB; ++p) gload_lds16(Bgp[p] + ko, Bsl + p * 4096 + ldsOff);
  };

  half8 bfr[2][NJ];                     // held across the whole tile

  // ew: -1 none, 0 -> waitv<0>, 6 -> waitv<6> before the closing barrier.
  auto tile = [&](int t, int slot, bool doStage, int ew) {
    const _Float16* Asl = As + slot * (BM * 64);
    const _Float16* Bsl = Bs + slot * (BN * 64);
    const int st = t + SLOTS - 1;       // stage target tile
    const int ss = (SLOTS == 2) ? (slot ^ 1) : (st % 3);
#pragma unroll
    for (int ph = 0; ph < PH; ++ph) {
      half8 afr[2][RP];
      if (ph == 0) {
#pragma unroll
        for (int kk = 0; kk < 2; ++kk) {
          const int pc = ((kk * 4 + q) ^ cx) << 3;
#pragma unroll
          for (int j = 0; j < NJ; ++j)
            bfr[kk][j] = *(const half8*)&Bsl[(bRow + 16 * j) * 64 + pc];
        }
      }
#pragma unroll
      for (int kk = 0; kk < 2; ++kk) {
        const int pc = ((kk * 4 + q) ^ cx) << 3;
#pragma unroll
        for (int r = 0; r < RP; ++r)
          afr[kk][r] = *(const half8*)&Asl[(aRow + 16 * (ph * RP + r)) * 64 + pc];
      }
      if (doStage && ph == 0) issueA(st, ss);
      if (doStage && ph == 1) issueB(st, ss);
      __builtin_amdgcn_s_barrier();
      asm volatile("s_waitcnt lgkmcnt(0)" ::: "memory");
      __builtin_amdgcn_sched_barrier(0);
      __builtin_amdgcn_s_setprio(1);
#pragma unroll
      for (int kk = 0; kk < 2; ++kk)
#pragma unroll
        for (int r = 0; r < RP; ++r)
#pragma unroll
          for (int j = 0; j < NJ; ++j)
            acc[ph * RP + r][j] = __builtin_amdgcn_mfma_f32_16x16x32_f16(
                afr[kk][r], bfr[kk][j], acc[ph * RP + r][j], 0, 0, 0);
      __builtin_amdgcn_s_setprio(0);
      if (ph == PH - 1) {
        if (ew == 6)      waitv<6>();   // t+1's loads landed; t+2's in flight
        else if (ew == 0) waitv<0>();
        if (ew >= 0) __builtin_amdgcn_s_barrier();  // closes t, publishes t+1
      } else {
        __builtin_amdgcn_s_barrier();
      }
    }
  };

  const int NT = K >> 6;
  if constexpr (SLOTS == 2) {
    issueA(0, 0); issueB(0, 0);
    waitv<0>(); __builtin_amdgcn_s_barrier();
    int cs = 0;
    for (int t = 0; t < NT - 1; ++t) {
      tile(t, cs, true, 0);             // stages t+1 -> cs^1 in ph0/ph1
      cs ^= 1;
    }
    tile(NT - 1, cs, false, -1);
  } else {
    static_assert(SLOTS == 3);
    issueA(0, 0); issueB(0, 0);
    issueA(1, 1); issueB(1, 1);
    waitv<6>(); __builtin_amdgcn_s_barrier();     // tile 0 landed
    int cs = 0;
    for (int t = 0; t < NT - 1; ++t) {
      const bool st = (t + 2 < NT);
      tile(t, cs, st, (t < NT - 2) ? 6 : 0);
      cs = (cs == 2) ? 0 : cs + 1;
    }
    tile(NT - 1, cs, false, -1);
  }
}

// BIAS_MODE: 0 none, 1 add per-col, 2 add per-row, 3 MUL per-row (invL).
// OUT_MODE: 0 fp16, 2 fp32.  SWZ: XCD grouping via ty = bflat % gridDim.y.
template<int BM, int BN, int WM, int WN, int SLOTS, int PH,
         int BIAS_MODE, int OUT_MODE, int SWZ>
__global__ __launch_bounds__(512, 2)
void gemm256_k(const _Float16* __restrict__ A, const _Float16* __restrict__ B,
               void* __restrict__ Cout, const float* __restrict__ bias,
               int lda, int ldb, int ldc, int K, float outScale)
{
  constexpr int MI = BM / WM / 16, NJ = BN / WN / 16;
  __shared__ __align__(16) _Float16 As[SLOTS * BM * 64];
  __shared__ __align__(16) _Float16 Bs[SLOTS * BN * 64];

  int tx, ty;
  if (SWZ) {
    const int bflat = blockIdx.y * gridDim.x + blockIdx.x;  // dispatch-linear
    ty = bflat % gridDim.y;
    tx = bflat / gridDim.y;
  } else {
    tx = blockIdx.x; ty = blockIdx.y;
  }
  const long rowBase = (long)ty * BM;
  const long colBase = (long)tx * BN;

  floatx4 acc[MI][NJ] = {};
  kloop_f<BM, BN, WM, WN, SLOTS, PH, MI, NJ>(A, B, rowBase, colBase, lda, ldb, K,
                                             As, Bs, acc);

  const int tid = threadIdx.x;
  const int w = tid >> 6, lane = tid & 63;
  const int q = lane >> 4, l15 = lane & 15;
  const int wr = w / WN, wcn = w & (WN - 1);
#pragma unroll
  for (int i = 0; i < MI; ++i) {
#pragma unroll
    for (int r = 0; r < 4; ++r) {
      const long rowg = rowBase + wr * (BM / WM) + 16 * i + q * 4 + r;
#pragma unroll
      for (int j = 0; j < NJ; ++j) {
        const long colg = colBase + wcn * (BN / WN) + 16 * j + l15;
        float v = acc[i][j][r];
        if (BIAS_MODE == 1) v += bias[colg];
        if (BIAS_MODE == 2) v += bias[rowg];
        if (BIAS_MODE == 3) v *= bias[rowg];
        v *= outScale;
        if (OUT_MODE == 2) ((float*)Cout)[rowg * ldc + colg] = v;
        else               ((_Float16*)Cout)[rowg * ldc + colg] = (_Float16)v;
      }
    }
  }
}

// U = exp(qkScale*(Q*K^T) + decay_bias - 4), fp16; per-(row,col-tile) sums.
// Engine A (256x256, 2-slot, 4-phase) + fused exp epilogue (validated v8/v9).
__global__ __launch_bounds__(512, 2)
void gemm_stats256_k(const _Float16* __restrict__ A, const _Float16* __restrict__ B,
                     const float* __restrict__ ts, _Float16* __restrict__ U,
                     float* __restrict__ part, int lda, int ldb, int N, int K,
                     float qkScale)
{
  constexpr int BM = 256, BN = 256, WM = 2, WN = 4, MI = 8, NJ = 4;
  __shared__ __align__(16) _Float16 As[2 * BM * 64];
  __shared__ __align__(16) _Float16 Bs[2 * BN * 64];
  __shared__ float trs[256], tcs[256];
  __shared__ float sL[2][4][128];
  const int tid = threadIdx.x;
  const long rowBase = (long)blockIdx.y * 256;
  const long colBase = (long)blockIdx.x * 256;

  if (tid < 256) {
    trs[tid] = ts[rowBase + tid];
    tcs[tid] = ts[colBase + tid];
  }

  floatx4 acc[MI][NJ] = {};
  kloop_f<BM, BN, WM, WN, 2, 4, MI, NJ>(A, B, rowBase, colBase, lda, ldb, K,
                                        As, Bs, acc);

  const int w = tid >> 6, lane = tid & 63;
  const int q = lane >> 4, l15 = lane & 15;
  const int wr = w >> 2, wcn = w & 3;
  const float inv_td = 1.0f / 86400.0f;
  // u = exp(s - 4); s = qk/32 + log-decay ~ qk/32 - |dt|/TD (exact to 2.2e-6).
#pragma unroll
  for (int i = 0; i < 8; ++i) {
#pragma unroll
    for (int r = 0; r < 4; ++r) {
      const int rowl = wr * 128 + 16 * i + q * 4 + r;
      const float tr = trs[rowl];
      float ls = 0.0f;
#pragma unroll
      for (int j = 0; j < 4; ++j) {
        const int coll = wcn * 64 + 16 * j + l15;
        const float sv = acc[i][j][r] * qkScale
                       - fabsf(tr - tcs[coll]) * inv_td - 4.0f;
        const float u = __expf(sv);
        ls += u;
        U[(rowBase + rowl) * (long)N + (colBase + coll)] = (_Float16)u;
      }
      for (int mask = 1; mask <= 8; mask <<= 1)
        ls += __shfl_xor(ls, mask, 64);
      if (l15 == 0) sL[wr][wcn][16 * i + 4 * q + r] = ls;
    }
  }
  __syncthreads();
  if (tid < 256) {
    const int wr2 = tid >> 7, rl = tid & 127;
    part[(rowBase + tid) * 32 + blockIdx.x] =
        sL[wr2][0][rl] + sL[wr2][1][rl] + sL[wr2][2][rl] + sL[wr2][3][rl];
  }
}

__global__ void combine_k(const float* __restrict__ part, float* __restrict__ invL) {
  const int r = blockIdx.x * 256 + threadIdx.x;
  float L = 0.0f;
  for (int c = 0; c < 32; ++c) L += part[(long)r * 32 + c];
  invL[r] = 1.0f / L;
}

// fp32 -> fp16, 4/thread
__global__ void cvt_k(const float* __restrict__ in, _Float16* __restrict__ out, int n) {
  const int i = (blockIdx.x * 256 + threadIdx.x) * 4;
  if (i >= n) return;
  const float4 v = *(const float4*)(in + i);
  half4 o = { (_Float16)v.x, (_Float16)v.y, (_Float16)v.z, (_Float16)v.w };
  *(half4*)(out + i) = o;
}

extern "C" void kernel_launch(void* const* d_in, const int* in_sizes, int n_in,
                              void* d_out, int out_size, void* d_ws, size_t ws_size,
                              hipStream_t stream)
{
  (void)in_sizes; (void)n_in; (void)out_size; (void)ws_size;
  const int N = 8192, D = 1024;
  const float* x  = (const float*)d_in[0];
  const float* ts = (const float*)d_in[1];
  const float* Wq = (const float*)d_in[2];
  const float* bq = (const float*)d_in[3];
  const float* Wk = (const float*)d_in[4];
  const float* bk = (const float*)d_in[5];
  const float* Wv = (const float*)d_in[6];
  const float* bv = (const float*)d_in[7];

  char* p = (char*)d_ws;
  auto grab = [&](size_t bytes) {
    char* r = p;
    p += (bytes + 255) & ~(size_t)255;
    return r;
  };
  _Float16* xh    = (_Float16*)grab((size_t)N * D * 2);
  _Float16* wqkh  = (_Float16*)grab((size_t)2 * D * D * 2); // Wq rows then Wk rows
  _Float16* wvh   = (_Float16*)grab((size_t)D * D * 2);
  _Float16* QKcat = (_Float16*)grab((size_t)N * 2 * D * 2); // [N x 2D], Q | K
  _Float16* VTh   = (_Float16*)grab((size_t)D * N * 2);     // V^T [D x N]
  _Float16* Uh    = (_Float16*)grab((size_t)N * N * 2);     // U = exp(S - 4)
  float*    part  = (float*)grab((size_t)N * 32 * sizeof(float));
  float*    invL  = (float*)grab((size_t)N * sizeof(float));
  float*    bcat  = (float*)grab((size_t)2 * D * sizeof(float));

  cvt_k<<<N * D / 1024, 256, 0, stream>>>(x,  xh,  N * D);
  cvt_k<<<D * D / 1024, 256, 0, stream>>>(Wq, wqkh,         D * D);
  cvt_k<<<D * D / 1024, 256, 0, stream>>>(Wk, wqkh + D * D, D * D);
  cvt_k<<<D * D / 1024, 256, 0, stream>>>(Wv, wvh, D * D);
  hipMemcpyAsync(bcat,     bq, D * sizeof(float), hipMemcpyDeviceToDevice, stream);
  hipMemcpyAsync(bcat + D, bk, D * sizeof(float), hipMemcpyDeviceToDevice, stream);

  dim3 blk(512);
  // [Q | K] = x [Wq;Wk]^T + [bq|bk]; engine A -> grid (8,32)=256 wg.
  gemm256_k<256, 256, 2, 4, 2, 4, 1, 0, 0><<<dim3(2 * D / 256, N / 256), blk, 0, stream>>>(
      xh, wqkh, QKcat, bcat, D, D, 2 * D, D, 1.0f);
  // V^T = Wv x^T + bv; engine B -> grid (64,4)=256 wg.
  gemm256_k<256, 128, 4, 2, 3, 2, 2, 0, 0><<<dim3(N / 128, D / 256), blk, 0, stream>>>(
      wvh, xh, VTh, bv, D, D, N, D, 1.0f);
  // U = exp(QK^T/32 + decay - 4) + partial row sums; engine A, 1024 wg.
  gemm_stats256_k<<<dim3(N / 256, N / 256), blk, 0, stream>>>(
      QKcat, QKcat + D, ts, Uh, part, 2 * D, 2 * D, N, D, 1.0f / 32.0f);
  combine_k<<<N / 256, 256, 0, stream>>>(part, invL);
  // O = (U V) * invL; engine B 3-slot -> grid (8,32)=256 wg, XCD swz.
  gemm256_k<256, 128, 4, 2, 3, 2, 3, 2, 1><<<dim3(D / 128, N / 256), blk, 0, stream>>>(
      Uh, VTh, d_out, invL, N, N, D, N, 1.0f);
}